// Round 1
// 588.738 us; speedup vs baseline: 1.3917x; 1.3917x over previous
//
#include <hip/hip_runtime.h>
#include <hip/hip_bf16.h>

#define B_  256
#define N_  343
#define C_  192
#define H_  6
#define D_  32
#define NW_ 32
#define NN_ (N_*N_)     /* 117649 */
#define TROWS 2197

typedef unsigned int  uint32;
typedef unsigned short u16;
typedef __attribute__((ext_vector_type(8))) short bf16x8;
typedef __attribute__((ext_vector_type(4))) float f32x4;

union frag8 { uint4 u4; bf16x8 h8; short s[8]; };

__device__ __forceinline__ float bf2f(u16 u){
  union { uint32 u; float f; } v; v.u = ((uint32)u) << 16; return v.f;
}
__device__ __forceinline__ u16 f2bf(float f){
  union { float f; uint32 u; } v; v.f = f;
  uint32 u = v.u;
  return (u16)((u + 0x7FFFu + ((u >> 16) & 1u)) >> 16);  // RNE
}

// Deterministic dtype sniff (fp32 vs bf16 input world) — see R2-R4 notes.
__device__ __forceinline__ bool detect_f32(const uint32* w){
  int c = 0;
  #pragma unroll
  for (int u = 0; u < 32; u++){
    int e = (w[u*37] >> 7) & 0xFF;
    c += (e > 150);
  }
  return c >= 3;
}
__device__ __forceinline__ float ldf(const void* p, size_t i, bool f32){
  return f32 ? ((const float*)p)[i] : bf2f(((const u16*)p)[i]);
}
__device__ __forceinline__ void stf(void* p, size_t i, float v, bool f32){
  if (f32) ((float*)p)[i] = v;
  else     ((u16*)p)[i]   = f2bf(v);
}

// biasg[h][i][j] = table[rel[i,j]][h], bf16. One-time gather -> hot loop streams.
__global__ void prep_biasg(const void* __restrict__ skip, const int* __restrict__ rel,
                           const void* __restrict__ table, u16* __restrict__ biasg){
  const bool F32 = detect_f32((const uint32*)skip);
  int idx = blockIdx.x*256 + threadIdx.x;
  if (idx >= NN_) return;
  int r = rel[idx];
  #pragma unroll
  for (int h = 0; h < H_; h++)
    biasg[(size_t)h*NN_ + idx] = f2bf(ldf(table, (size_t)r*H_ + h, F32));
}

// ---- attn LDS layout (u16 units) ----
// [0,6400): skc[32][200] during KV phase; pls[wave][16][40] (8 waves) during attn
#define KLS_OFF 6400                 // kls[352][40] K rows, B-operand layout
#define VT_OFF  (KLS_OFF + 352*40)   // 20480: vT[32][360] V transposed
#define SMEM_U16 (VT_OFF + 32*360)   /* 32000 u16 = 64000 B */

// 512 threads / 8 waves: occupancy was the limiter (23%, 2 waves/SIMD) — same
// LDS tile now shared by 8 waves -> 2 blocks x 8 waves = 16 waves/CU (~46%).
__global__ __launch_bounds__(512, 4) void attn_fused(
    const void* __restrict__ skip, const void* __restrict__ x_up,
    const void* __restrict__ mask, const u16* __restrict__ biasg,
    const void* __restrict__ kv_w, const void* __restrict__ kv_b,
    void* __restrict__ out){
  __shared__ __align__(16) u16 sm[SMEM_U16];
  const bool F32 = detect_f32((const uint32*)skip);
  const int bid = blockIdx.x;
  const int b = bid / H_, h = bid % H_;
  const int w = b & (NW_-1);
  const int t = threadIdx.x;
  const int lane = t & 63, wave = t >> 6;          // wave 0..7
  const int n16 = lane & 15, q = lane >> 4;

  // ---- KV GEMM via MFMA: wave = (row-half, col-tile). colt: K:0,1  V:2,3 ----
  const int colt = wave & 3;
  const int half = wave >> 2;                      // which 16-row half of the 32-row chunk
  const int gcol = (colt < 2) ? (h*D_ + colt*16 + n16)
                              : (C_ + h*D_ + (colt-2)*16 + n16);
  const float kvb = ldf(kv_b, gcol, F32);
  frag8 bw[6];                        // kv_w B-frags: depend on ks only -> hoisted
  #pragma unroll
  for (int ks = 0; ks < 6; ks++)
    #pragma unroll
    for (int j = 0; j < 8; j++)
      bw[ks].s[j] = (short)f2bf(ldf(kv_w, (size_t)(ks*32 + q*8 + j)*384 + gcol, F32));

  for (int rc = 0; rc < 11; rc++){                 // 11 chunks x 32 rows = 352
    __syncthreads();
    for (int u = t; u < 32*C_; u += 512){
      int r = u / C_, c = u % C_;
      int grow = rc*32 + r;
      float v = (grow < N_) ? ldf(skip, ((size_t)b*N_ + grow)*C_ + c, F32) : 0.f;
      sm[r*200 + c] = f2bf(v);
    }
    __syncthreads();
    f32x4 acc = {0.f, 0.f, 0.f, 0.f};
    #pragma unroll
    for (int ks = 0; ks < 6; ks++){
      frag8 a;  a.u4 = *(const uint4*)&sm[(half*16 + n16)*200 + ks*32 + q*8];
      acc = __builtin_amdgcn_mfma_f32_16x16x32_bf16(a.h8, bw[ks].h8, acc, 0, 0, 0);
    }
    #pragma unroll
    for (int r = 0; r < 4; r++){       // D[m=q*4+r][n=n16]; rows up to 351 (finite pad)
      int grow = rc*32 + half*16 + q*4 + r;
      u16 val = f2bf(acc[r] + kvb);
      if (colt < 2) sm[KLS_OFF + grow*40 + colt*16 + n16] = val;        // kls[j][d]
      else          sm[VT_OFF + ((colt-2)*16 + n16)*360 + grow] = val;  // vT[d][j]
    }
  }
  __syncthreads();

  // ---- attention: per-wave i-tiles, pls private -> no more barriers ----
  const float scale = 0.17677669529663687f;
  const size_t mwb = (size_t)w*NN_;
  const u16* bg = biasg + (size_t)h*NN_;
  u16* pls = &sm[wave*640];            // 16x40, per-wave private
  for (int it = wave; it < 22; it += 8){
    int i0 = it*16;
    // stage Q tile coalesced: lane -> row i0+(lane>>2), cols (lane&3)*8..+7
    {
      int rrow = min(i0 + (lane >> 2), N_-1);
      int col0 = (lane & 3)*8;
      size_t gb = ((size_t)b*N_ + rrow)*C_ + h*D_ + col0;
      u16* dst = &pls[(lane >> 2)*40 + col0];
      #pragma unroll
      for (int m = 0; m < 8; m++) dst[m] = f2bf(ldf(x_up, gb + m, F32) * scale);
    }
    frag8 aq; aq.u4 = *(const uint4*)&pls[n16*40 + q*8];   // A[m=n16][k=d] (same-wave order)
    f32x4 O0 = {0.f,0.f,0.f,0.f}, O1 = {0.f,0.f,0.f,0.f};
    float lp[4] = {0.f, 0.f, 0.f, 0.f};
    int ic[4];
    #pragma unroll
    for (int r = 0; r < 4; r++) ic[r] = min(i0 + q*4 + r, N_-1);
    for (int jc = 0; jc < 11; jc++){
      int j0 = jc*32;
      int ja = j0 + n16, jb = j0 + 16 + n16;
      int jac = min(ja, N_-1), jbc = min(jb, N_-1);
      // issue bias+mask loads early (independent of MFMA)
      float bma[4], bmb[4];
      #pragma unroll
      for (int r = 0; r < 4; r++){
        size_t rb = (size_t)ic[r]*N_;
        bma[r] = bf2f(bg[rb + jac]) + ldf(mask, mwb + rb + jac, F32);
        bmb[r] = bf2f(bg[rb + jbc]) + ldf(mask, mwb + rb + jbc, F32);
      }
      frag8 bk0, bk1;                  // B[n=j_local][k=d]
      bk0.u4 = *(const uint4*)&sm[KLS_OFF + (j0 + n16)*40 + q*8];
      bk1.u4 = *(const uint4*)&sm[KLS_OFF + (j0 + 16 + n16)*40 + q*8];
      f32x4 z = {0.f,0.f,0.f,0.f};
      f32x4 s0 = __builtin_amdgcn_mfma_f32_16x16x32_bf16(aq.h8, bk0.h8, z, 0,0,0);
      f32x4 s1 = __builtin_amdgcn_mfma_f32_16x16x32_bf16(aq.h8, bk1.h8, z, 0,0,0);
      #pragma unroll
      for (int r = 0; r < 4; r++){
        float pa = (ja < N_) ? __expf(s0[r] + bma[r] - 12.f) : 0.f;  // offset cancels in softmax
        float pb = (jb < N_) ? __expf(s1[r] + bmb[r] - 12.f) : 0.f;
        lp[r] += pa + pb;
        pls[(q*4 + r)*40 + n16]      = f2bf(pa);   // C-layout -> LDS
        pls[(q*4 + r)*40 + 16 + n16] = f2bf(pb);
      }
      frag8 ap; ap.u4 = *(const uint4*)&pls[n16*40 + q*8];   // A[m][k=j_local]
      frag8 bv0, bv1;                  // B[n=d_local][k=j]
      bv0.u4 = *(const uint4*)&sm[VT_OFF + n16*360 + j0 + q*8];
      bv1.u4 = *(const uint4*)&sm[VT_OFF + (16 + n16)*360 + j0 + q*8];
      O0 = __builtin_amdgcn_mfma_f32_16x16x32_bf16(ap.h8, bv0.h8, O0, 0,0,0);
      O1 = __builtin_amdgcn_mfma_f32_16x16x32_bf16(ap.h8, bv1.h8, O1, 0,0,0);
    }
    #pragma unroll
    for (int msk = 1; msk < 16; msk <<= 1){
      #pragma unroll
      for (int r = 0; r < 4; r++) lp[r] += __shfl_xor(lp[r], msk, 64);
    }
    #pragma unroll
    for (int r = 0; r < 4; r++){
      int i = i0 + q*4 + r;
      if (i < N_){
        float rl = 1.f / lp[r];
        size_t ob = ((size_t)b*N_ + i)*C_ + h*D_;
        stf(out, ob + n16,      O0[r]*rl, F32);
        stf(out, ob + 16 + n16, O1[r]*rl, F32);
      }
    }
  }
}

// MFMA in-place projection: block = 128 rows x 192 cols (686*128 = 87808 exact).
__global__ __launch_bounds__(256, 2) void proj_k(void* __restrict__ io,
                                                 const void* __restrict__ pw,
                                                 const void* __restrict__ pb,
                                                 const void* __restrict__ skip){
  __shared__ __align__(16) u16 xs[128*200];   // 51200 B
  const bool F32 = detect_f32((const uint32*)skip);
  const int t = threadIdx.x;
  const int lane = t & 63, wave = t >> 6;
  const int n16 = lane & 15, q = lane >> 4;
  const size_t row0 = (size_t)blockIdx.x * 128;

  for (int u = t; u < 128*C_; u += 256){
    int r = u / C_, c = u % C_;
    xs[r*200 + c] = f2bf(ldf(io, (row0 + r)*C_ + c, F32));
  }
  // B-frags for this wave's 3 col-tiles (reused across all 8 row-tiles)
  frag8 bwf[3][6];
  float pbv[3];
  #pragma unroll
  for (int c3 = 0; c3 < 3; c3++){
    int col = (wave*3 + c3)*16 + n16;
    pbv[c3] = ldf(pb, col, F32);
    #pragma unroll
    for (int ks = 0; ks < 6; ks++)
      #pragma unroll
      for (int j = 0; j < 8; j++)
        bwf[c3][ks].s[j] = (short)f2bf(ldf(pw, (size_t)(ks*32 + q*8 + j)*C_ + col, F32));
  }
  __syncthreads();
  for (int rt = 0; rt < 8; rt++){
    frag8 af[6];
    #pragma unroll
    for (int ks = 0; ks < 6; ks++)
      af[ks].u4 = *(const uint4*)&xs[(rt*16 + n16)*200 + ks*32 + q*8];
    #pragma unroll
    for (int c3 = 0; c3 < 3; c3++){
      f32x4 acc = {0.f,0.f,0.f,0.f};
      #pragma unroll
      for (int ks = 0; ks < 6; ks++)
        acc = __builtin_amdgcn_mfma_f32_16x16x32_bf16(af[ks].h8, bwf[c3][ks].h8, acc, 0,0,0);
      #pragma unroll
      for (int r = 0; r < 4; r++)
        stf(io, (row0 + rt*16 + q*4 + r)*C_ + (wave*3 + c3)*16 + n16, acc[r] + pbv[c3], F32);
    }
  }
}

extern "C" void kernel_launch(void* const* d_in, const int* in_sizes, int n_in,
                              void* d_out, int out_size, void* d_ws, size_t ws_size,
                              hipStream_t stream){
  (void)in_sizes; (void)n_in; (void)out_size; (void)ws_size;
  const void* skip  = d_in[0];
  const void* x_up  = d_in[1];
  const void* mask  = d_in[2];
  const int*  rel   = (const int*)d_in[3];
  const void* table = d_in[4];
  const void* kv_w  = d_in[5];
  const void* kv_b  = d_in[6];
  const void* pw    = d_in[7];
  const void* pb    = d_in[8];
  u16* biasg = (u16*)d_ws;   // 705894 bf16 = 1.41 MB

  prep_biasg<<<(NN_+255)/256, 256, 0, stream>>>(skip, rel, table, biasg);
  attn_fused<<<B_*H_, 512, 0, stream>>>(skip, x_up, mask, biasg, kv_w, kv_b, d_out);
  proj_k    <<<87808/128, 256, 0, stream>>>(d_out, pw, pb, skip);
}